// Round 6
// baseline (237.019 us; speedup 1.0000x reference)
//
#include <hip/hip_runtime.h>

// Sparsemax, last dim d=1024, 32768 rows, fp32. One wave processes 4 rows,
// software-pipelined: row i+1's global loads are issued before row i's
// Newton chain, so memory latency hides under compute (vmcnt(4) waits).
// Zero DS-pipe traffic: DPP reductions + ballot/popcount. Newton
// t' = t + (S(t)-1)/n(t) from t0 = max-1 on the <=3 per-lane candidates
// z > max-1 (E[K/row]~14); wave-uniform fallback if any lane overflows.

#define ROW_D 1024
#define RPW   4          // rows per wave
#define NEG_PAD -3.0e38f

typedef float f4 __attribute__((ext_vector_type(4)));

template <int CTRL, int RMASK>
__device__ __forceinline__ float dpp_mv(float x) {
    return __builtin_bit_cast(float, __builtin_amdgcn_update_dpp(
        __builtin_bit_cast(int, x), __builtin_bit_cast(int, x),
        CTRL, RMASK, 0xf, false));
}
__device__ __forceinline__ float dpp_sum_to63(float x) {
    x += dpp_mv<0x111, 0xf>(x);   // row_shr:1
    x += dpp_mv<0x112, 0xf>(x);   // row_shr:2
    x += dpp_mv<0x114, 0xf>(x);   // row_shr:4
    x += dpp_mv<0x118, 0xf>(x);   // row_shr:8
    x += dpp_mv<0x142, 0xa>(x);   // row_bcast15
    x += dpp_mv<0x143, 0xc>(x);   // row_bcast31
    return x;
}
__device__ __forceinline__ float dpp_max_to63(float x) {
    x = fmaxf(x, dpp_mv<0x111, 0xf>(x));
    x = fmaxf(x, dpp_mv<0x112, 0xf>(x));
    x = fmaxf(x, dpp_mv<0x114, 0xf>(x));
    x = fmaxf(x, dpp_mv<0x118, 0xf>(x));
    x = fmaxf(x, dpp_mv<0x142, 0xa>(x));
    x = fmaxf(x, dpp_mv<0x143, 0xc>(x));
    return x;
}
__device__ __forceinline__ float bcast63(float x) {
    return __builtin_bit_cast(float,
        __builtin_amdgcn_readlane(__builtin_bit_cast(int, x), 63));
}

// tau for one row held in registers (16 elems/lane).
__device__ __forceinline__ float row_tau(const f4* __restrict__ v) {
    float mj[4];
#pragma unroll
    for (int j = 0; j < 4; ++j)
        mj[j] = fmaxf(fmaxf(v[j].x, v[j].y), fmaxf(v[j].z, v[j].w));
    float m = fmaxf(fmaxf(mj[0], mj[1]), fmaxf(mj[2], mj[3]));
    m = bcast63(dpp_max_to63(m));
    const float lo0 = m - 1.0f;

    // Per-lane collapse to <=3 candidates > lo0.
    float c0 = NEG_PAD, c1 = NEG_PAD, c2 = NEG_PAD;
    int cnt = 0;
#pragma unroll
    for (int j = 0; j < 4; ++j) {
        const float e[4] = {v[j].x, v[j].y, v[j].z, v[j].w};
#pragma unroll
        for (int c = 0; c < 4; ++c) {
            const bool g = e[c] > lo0;
            c2 = g ? c1 : c2;
            c1 = g ? c0 : c1;
            c0 = g ? e[c] : c0;
            cnt += g ? 1 : 0;
        }
    }

    float t = lo0;
    if (__ballot(cnt > 3) == 0ULL) {
#pragma unroll 1
        for (int it = 0; it < 16; ++it) {
            const float d0 = c0 - t, d1 = c1 - t, d2 = c2 - t;
            const float s = fmaxf(d0, 0.0f) + (fmaxf(d1, 0.0f) + fmaxf(d2, 0.0f));
            int n = __popcll(__ballot(d0 > 0.0f));
            n += __popcll(__ballot(d1 > 0.0f));
            n += __popcll(__ballot(d2 > 0.0f));
            const float S = bcast63(dpp_sum_to63(s));
            const float t2 = t + (S - 1.0f) / (float)n;
            if (t2 - t <= 1e-6f) { t = t2; break; }
            t = t2;
        }
    } else {
        // Rare wave-uniform fallback: Newton over all 16 elems/lane.
#pragma unroll 1
        for (int it = 0; it < 24; ++it) {
            float sj[4];
            int n = 0;
#pragma unroll
            for (int j = 0; j < 4; ++j) {
                const float d0 = v[j].x - t, d1 = v[j].y - t;
                const float d2 = v[j].z - t, d3 = v[j].w - t;
                sj[j] = (fmaxf(d0, 0.0f) + fmaxf(d1, 0.0f)) +
                        (fmaxf(d2, 0.0f) + fmaxf(d3, 0.0f));
                n += __popcll(__ballot(d0 > 0.0f));
                n += __popcll(__ballot(d1 > 0.0f));
                n += __popcll(__ballot(d2 > 0.0f));
                n += __popcll(__ballot(d3 > 0.0f));
            }
            const float S = bcast63(dpp_sum_to63((sj[0] + sj[1]) + (sj[2] + sj[3])));
            const float t2 = t + (S - 1.0f) / (float)n;
            if (t2 - t <= 1e-6f) { t = t2; break; }
            t = t2;
        }
    }
    return t;
}

__global__ __launch_bounds__(256) void sparsemax_kernel(
    const float* __restrict__ z, float* __restrict__ out, int nrows) {
    const int lane  = (int)(threadIdx.x & 63u);
    const int wslot = (int)(threadIdx.x >> 6);
    const int base  = ((int)(blockIdx.x << 2) + wslot) * RPW;
    if (base >= nrows) return;

    // Prologue: load row base.
    f4 nxt[4], cur[4];
    {
        const f4* zr = reinterpret_cast<const f4*>(z + (size_t)base * ROW_D);
#pragma unroll
        for (int j = 0; j < 4; ++j) nxt[j] = zr[lane + 64 * j];
    }

#pragma unroll
    for (int i = 0; i < RPW; ++i) {
        const int row = (base + i < nrows) ? base + i : nrows - 1;
#pragma unroll
        for (int j = 0; j < 4; ++j) cur[j] = nxt[j];

        // Prefetch next row BEFORE the serial tau chain; these 4 loads stay
        // outstanding (vmcnt(4)) while Newton runs on cur.
        if (i + 1 < RPW) {
            const int nrow = (base + i + 1 < nrows) ? base + i + 1 : nrows - 1;
            const f4* zn = reinterpret_cast<const f4*>(z + (size_t)nrow * ROW_D);
#pragma unroll
            for (int j = 0; j < 4; ++j) nxt[j] = zn[lane + 64 * j];
        }

        const float t = row_tau(cur);

        f4* po = reinterpret_cast<f4*>(out + (size_t)row * ROW_D);
#pragma unroll
        for (int j = 0; j < 4; ++j) {
            f4 o;
            o.x = fmaxf(cur[j].x - t, 0.0f);
            o.y = fmaxf(cur[j].y - t, 0.0f);
            o.z = fmaxf(cur[j].z - t, 0.0f);
            o.w = fmaxf(cur[j].w - t, 0.0f);
            __builtin_nontemporal_store(o, po + lane + 64 * j);
        }
    }
}

extern "C" void kernel_launch(void* const* d_in, const int* in_sizes, int n_in,
                              void* d_out, int out_size, void* d_ws, size_t ws_size,
                              hipStream_t stream) {
    const float* z = (const float*)d_in[0];
    float* out = (float*)d_out;
    const int n = in_sizes[0];          // 8*4096*1024
    const int nrows = n / ROW_D;        // 32768
    const int rows_per_block = 4 * RPW; // 4 waves x 4 rows
    const int blocks = (nrows + rows_per_block - 1) / rows_per_block;  // 2048
    sparsemax_kernel<<<blocks, 256, 0, stream>>>(z, out, nrows);
}